// Round 1
// baseline (599.288 us; speedup 1.0000x reference)
//
#include <hip/hip_runtime.h>
#include <math.h>

#define M_ROWS 65536
#define NSPLINE 32
#define KDIM 48          // 32 (z2) + 16 (c)
#define COLS 1056        // 32 * 33
#define NSPLIT 4
#define NS (NSPLINE / NSPLIT)   // 8 splines per block

// ---------------------------------------------------------------------------
// Transpose W (48 x 1056, row-major) -> WT (1056 x 48, row-major) in d_ws.
// Each output column's 48 weights become contiguous => s_load_dwordx16 x3.
// ---------------------------------------------------------------------------
__global__ void transpose_W(const float* __restrict__ W, float* __restrict__ WT) {
    int t = blockIdx.x * 256 + threadIdx.x;
    if (t >= KDIM * COLS) return;
    int col = t / KDIM;
    int k   = t % KDIM;
    WT[t] = W[k * COLS + col];   // writes coalesced
}

// ---------------------------------------------------------------------------
// x[:, :32] = z2 = z[:, 32:64]
// ---------------------------------------------------------------------------
__global__ void copy_z2(const float* __restrict__ z, float* __restrict__ out) {
    int t = blockIdx.x * 256 + threadIdx.x;   // over M*32
    int m = t >> 5, j = t & 31;
    out[(size_t)m * 64 + j] = z[(size_t)m * 64 + 32 + j];
}

// ---------------------------------------------------------------------------
// Main fused kernel: per (row, spline) compute 33-col affine then the
// quadratic spline. Thread = row; block covers NS splines sequentially.
// W streamed via block-uniform (scalar) loads -> SGPR-broadcast FMAs.
// ---------------------------------------------------------------------------
__global__ void __launch_bounds__(256) spline_kernel(
    const float* __restrict__ z, const float* __restrict__ c,
    const float* __restrict__ WT, const float* __restrict__ bias,
    float* __restrict__ out)
{
    const int r  = blockIdx.x * 256 + threadIdx.x;
    const int n0 = blockIdx.y * NS;

    // A = z2c row: [ z[r,32:64] , c[r,0:16] ]  (48 fp32 in VGPRs)
    float A[KDIM];
    {
        const float4* z2p = reinterpret_cast<const float4*>(z + (size_t)r * 64 + 32);
        #pragma unroll
        for (int i = 0; i < 8; ++i) {
            float4 v = z2p[i];
            A[4*i] = v.x; A[4*i+1] = v.y; A[4*i+2] = v.z; A[4*i+3] = v.w;
        }
        const float4* cp = reinterpret_cast<const float4*>(c + (size_t)r * 16);
        #pragma unroll
        for (int i = 0; i < 4; ++i) {
            float4 v = cp[i];
            A[32+4*i] = v.x; A[32+4*i+1] = v.y; A[32+4*i+2] = v.z; A[32+4*i+3] = v.w;
        }
    }

    float ld_sum = 0.0f;

    #pragma unroll 1
    for (int s = 0; s < NS; ++s) {
        const int n = n0 + s;
        const float* __restrict__ wc = WT + (size_t)n * 33 * KDIM;  // uniform
        const float* __restrict__ bb = bias + n * 33;               // uniform

        // ---- widths: cols 17..32 -> softmax -> affine -------------------
        float w[16];
        float sew = 0.f;
        #pragma unroll
        for (int i = 0; i < 16; ++i) {
            const float* wk = wc + (17 + i) * KDIM;
            float a0 = bb[17 + i], a1 = 0.f, a2 = 0.f, a3 = 0.f;
            #pragma unroll
            for (int k = 0; k < KDIM; k += 4) {
                a0 = fmaf(A[k    ], wk[k    ], a0);
                a1 = fmaf(A[k + 1], wk[k + 1], a1);
                a2 = fmaf(A[k + 2], wk[k + 2], a2);
                a3 = fmaf(A[k + 3], wk[k + 3], a3);
            }
            float e = __expf((a0 + a1) + (a2 + a3));
            w[i] = e;
            sew += e;
        }
        const float inv_sew = 0.984f / sew;   // (1 - 16*MIN_BW) / sum
        #pragma unroll
        for (int i = 0; i < 16; ++i) w[i] = 0.001f + w[i] * inv_sew;

        // ---- heights: cols 0..16 -> softplus -> normalize -> affine -----
        float h[17];
        #pragma unroll
        for (int i = 0; i < 17; ++i) {
            const float* wk = wc + i * KDIM;
            float a0 = bb[i], a1 = 0.f, a2 = 0.f, a3 = 0.f;
            #pragma unroll
            for (int k = 0; k < KDIM; k += 4) {
                a0 = fmaf(A[k    ], wk[k    ], a0);
                a1 = fmaf(A[k + 1], wk[k + 1], a1);
                a2 = fmaf(A[k + 2], wk[k + 2], a2);
                a3 = fmaf(A[k + 3], wk[k + 3], a3);
            }
            float t = (a0 + a1) + (a2 + a3);
            h[i] = log1pf(__expf(t)) + 0.001f;   // softplus + 0.001
        }
        float area = 0.f;
        #pragma unroll
        for (int i = 0; i < 16; ++i) area += (h[i] + h[i + 1]) * 0.5f * w[i];
        const float inv_area = 0.999f / area;    // (1 - MIN_BH) / area
        #pragma unroll
        for (int i = 0; i < 17; ++i) h[i] = 0.001f + h[i] * inv_area;

        // ---- bin select (monotone overwrite == gather by bin_idx) -------
        const float in = z[(size_t)r * 64 + n];  // z1[r, n]
        float loc = 0.f, cdfl = 0.f;
        float sel_loc = 0.f, sel_w = w[0], sel_cdf = 0.f;
        float sel_lh = h[0], sel_rh = h[1];
        #pragma unroll
        for (int bn = 1; bn < 16; ++bn) {
            cdfl = fmaf((h[bn - 1] + h[bn]) * 0.5f, w[bn - 1], cdfl);
            loc += w[bn - 1];
            if (in >= loc) {   // monotone: last true wins
                sel_loc = loc; sel_w = w[bn]; sel_cdf = cdfl;
                sel_lh = h[bn]; sel_rh = h[bn + 1];
            }
        }

        const float alpha = (in - sel_loc) / sel_w;
        const float dh    = sel_rh - sel_lh;
        float o = ((0.5f * dh * sel_w) * alpha + sel_lh * sel_w) * alpha + sel_cdf;
        o = fminf(fmaxf(o, 0.0f), 1.0f);
        out[(size_t)r * 64 + 32 + n] = o;
        ld_sum += __logf(fmaf(alpha, dh, sel_lh));
    }

    // logdet partial sum (4 blocks contribute per row)
    atomicAdd(out + (size_t)M_ROWS * 64 + r, ld_sum);
}

extern "C" void kernel_launch(void* const* d_in, const int* in_sizes, int n_in,
                              void* d_out, int out_size, void* d_ws, size_t ws_size,
                              hipStream_t stream) {
    const float* c = (const float*)d_in[0];   // (M, 16)
    const float* z = (const float*)d_in[1];   // (M, 64)
    const float* W = (const float*)d_in[2];   // (48, 1056)
    const float* b = (const float*)d_in[3];   // (1056,)
    float* out = (float*)d_out;               // M*64 (x) then M (logdet)
    float* WT  = (float*)d_ws;                // 1056*48 fp32 = 198 KiB

    // zero the logdet region (harness poisons d_out with 0xAA)
    hipMemsetAsync(out + (size_t)M_ROWS * 64, 0, M_ROWS * sizeof(float), stream);

    transpose_W<<<(KDIM * COLS + 255) / 256, 256, 0, stream>>>(W, WT);
    copy_z2<<<(M_ROWS * 32) / 256, 256, 0, stream>>>(z, out);
    spline_kernel<<<dim3(M_ROWS / 256, NSPLIT), 256, 0, stream>>>(z, c, WT, b, out);
}

// Round 2
// 199.560 us; speedup vs baseline: 3.0030x; 3.0030x over previous
//
#include <hip/hip_runtime.h>
#include <hip/hip_bf16.h>
#include <math.h>

#define M_ROWS 65536
#define NSPLINE 32
#define BM 64            // rows per block
#define WROWS 16         // rows per wave
#define GROUP 4          // splines per iteration
#define NITER (NSPLINE / GROUP)   // 8
#define YSTRIDE 33       // LDS row stride (odd -> conflict-free)

typedef __attribute__((ext_vector_type(8))) short short8;
typedef __attribute__((ext_vector_type(4))) float floatx4;

__device__ __forceinline__ short f2bf(float f) {
    union { __hip_bfloat16 h; short s; } u;
    u.h = __float2bfloat16(f);
    return u.s;
}

// ---------------------------------------------------------------------------
// Pack W (48x1056 fp32) + bias (1056) into MFMA B-fragment layout, bf16.
// WB[sp][t][half][lane][j], sp<32 splines, t<3 col-tiles (cols 33..47 pad=0),
// half<2 (K 0..31 / 32..63), lane<64, j<8.
//   col = sp*33 + t*16 + (lane&15)   (valid if t*16+(lane&15) < 33)
//   k   = half*32 + (lane>>4)*8 + j  (k<48: W[k][col]; k==48: bias[col]; else 0)
// ---------------------------------------------------------------------------
__global__ void pack_W(const float* __restrict__ W, const float* __restrict__ b,
                       short* __restrict__ WB) {
    int idx = blockIdx.x * 256 + threadIdx.x;     // 32*3*2*64*8 = 98304
    int j    = idx & 7;
    int lane = (idx >> 3) & 63;
    int half = (idx >> 9) & 1;
    int tmp  = idx >> 10;
    int t    = tmp % 3;
    int sp   = tmp / 3;
    int cl = t * 16 + (lane & 15);
    int k  = half * 32 + (lane >> 4) * 8 + j;
    float v = 0.0f;
    if (cl < 33) {
        int col = sp * 33 + cl;
        if (k < 48)       v = W[k * 1056 + col];
        else if (k == 48) v = b[col];
    }
    WB[idx] = f2bf(v);
}

// ---------------------------------------------------------------------------
// Fused: bf16 MFMA GEMM (y = [z2,c,1] @ [W;b]) -> LDS transpose -> spline.
// Wave w owns rows blockIdx.x*64 + w*16 .. +15 exclusively.
// ---------------------------------------------------------------------------
__global__ void __launch_bounds__(256, 4) fused_kernel(
    const float* __restrict__ z, const float* __restrict__ c,
    const short* __restrict__ WB, float* __restrict__ out)
{
    __shared__ float lds_y[4 * 64 * YSTRIDE];    // 33.8 KB, per-wave regions

    const int tid  = threadIdx.x;
    const int w    = tid >> 6;
    const int lane = tid & 63;
    const int q    = lane >> 4;        // quad 0..3
    const int cc   = lane & 15;
    const int row_base = blockIdx.x * BM + w * WROWS;
    float* lds_wv = lds_y + w * (64 * YSTRIDE);

    // ---- z2 passthrough: out[:, :32] = z[:, 32:64] for this wave's rows ----
    #pragma unroll
    for (int it = 0; it < 2; ++it) {
        int idx = it * 64 + lane;                 // 0..127 = 16 rows x 8 float4
        int rr  = row_base + (idx >> 3);
        int v4  = idx & 7;
        float4 val = *(const float4*)(z + (size_t)rr * 64 + 32 + v4 * 4);
        *(float4*)(out + (size_t)rr * 64 + v4 * 4) = val;
    }

    // ---- A fragments (persist all kernel): A[m=cc][k], k=(q*8+j) ----------
    short8 a0, a1;
    {
        const float* zr = z + (size_t)(row_base + cc) * 64 + 32;
        float4 v0 = *(const float4*)(zr + q * 8);
        float4 v1 = *(const float4*)(zr + q * 8 + 4);
        a0[0]=f2bf(v0.x); a0[1]=f2bf(v0.y); a0[2]=f2bf(v0.z); a0[3]=f2bf(v0.w);
        a0[4]=f2bf(v1.x); a0[5]=f2bf(v1.y); a0[6]=f2bf(v1.z); a0[7]=f2bf(v1.w);
        if (q < 2) {
            const float* cr = c + (size_t)(row_base + cc) * 16 + q * 8;
            float4 u0 = *(const float4*)cr;
            float4 u1 = *(const float4*)(cr + 4);
            a1[0]=f2bf(u0.x); a1[1]=f2bf(u0.y); a1[2]=f2bf(u0.z); a1[3]=f2bf(u0.w);
            a1[4]=f2bf(u1.x); a1[5]=f2bf(u1.y); a1[6]=f2bf(u1.z); a1[7]=f2bf(u1.w);
        } else {
            #pragma unroll
            for (int j = 0; j < 8; ++j) a1[j] = 0;
            if (q == 2) a1[0] = (short)0x3F80;   // bf16 1.0 at k=48 (bias row)
        }
    }

    float ld_acc = 0.0f;

    #pragma unroll 1
    for (int g = 0; g < NITER; ++g) {
        __syncthreads();   // prior iteration's LDS reads are done

        // ---- GEMM: 4 splines x 3 col-tiles, write y straight to LDS ------
        #pragma unroll
        for (int sp = 0; sp < GROUP; ++sp) {
            const int spg = g * GROUP + sp;
            #pragma unroll
            for (int t = 0; t < 3; ++t) {
                const short8* p = (const short8*)WB + (size_t)(spg * 3 + t) * 128 + lane;
                short8 b0 = p[0];
                short8 b1 = p[64];
                floatx4 acc = {0.f, 0.f, 0.f, 0.f};
                acc = __builtin_amdgcn_mfma_f32_16x16x32_bf16(a0, b0, acc, 0, 0, 0);
                acc = __builtin_amdgcn_mfma_f32_16x16x32_bf16(a1, b1, acc, 0, 0, 0);
                // D layout: col = cc (=lane&15), row = q*4 + reg
                if (t < 2 || cc == 0) {
                    float* dst = lds_wv + (sp * 16 + q * 4) * YSTRIDE + t * 16 + cc;
                    dst[0]          = acc[0];
                    dst[YSTRIDE]    = acc[1];
                    dst[2 * YSTRIDE]= acc[2];
                    dst[3 * YSTRIDE]= acc[3];
                }
            }
        }
        __syncthreads();

        // ---- spline: task = (row=cc, spline n=g*4+q), all 64 lanes busy --
        const int n = g * GROUP + q;
        const float* my = lds_wv + (q * 16 + cc) * YSTRIDE;   // = lane*33
        const float in = z[(size_t)(row_base + cc) * 64 + n];

        float wd[16];
        float sew = 0.f;
        #pragma unroll
        for (int i = 0; i < 16; ++i) {
            float e = __expf(my[17 + i]);
            wd[i] = e; sew += e;
        }
        const float inv_sew = 0.984f / sew;        // (1 - 16*MIN_BW)/sum
        #pragma unroll
        for (int i = 0; i < 16; ++i) wd[i] = 0.001f + wd[i] * inv_sew;

        float h[17];
        #pragma unroll
        for (int i = 0; i < 17; ++i)
            h[i] = log1pf(__expf(my[i])) + 0.001f; // softplus + 0.001

        float area = 0.f;
        #pragma unroll
        for (int i = 0; i < 16; ++i) area += (h[i] + h[i + 1]) * 0.5f * wd[i];
        const float inv_area = 0.999f / area;      // (1 - MIN_BH)/area
        #pragma unroll
        for (int i = 0; i < 17; ++i) h[i] = 0.001f + h[i] * inv_area;

        float loc = 0.f, cdfl = 0.f;
        float sel_loc = 0.f, sel_w = wd[0], sel_cdf = 0.f;
        float sel_lh = h[0], sel_rh = h[1];
        #pragma unroll
        for (int bn = 1; bn < 16; ++bn) {
            cdfl = fmaf((h[bn - 1] + h[bn]) * 0.5f, wd[bn - 1], cdfl);
            loc += wd[bn - 1];
            if (in >= loc) {                        // monotone: last true wins
                sel_loc = loc; sel_w = wd[bn]; sel_cdf = cdfl;
                sel_lh = h[bn]; sel_rh = h[bn + 1];
            }
        }

        const float alpha = (in - sel_loc) / sel_w;
        const float dh    = sel_rh - sel_lh;
        float o = ((0.5f * dh * sel_w) * alpha + sel_lh * sel_w) * alpha + sel_cdf;
        o = fminf(fmaxf(o, 0.0f), 1.0f);
        out[(size_t)(row_base + cc) * 64 + 32 + n] = o;
        ld_acc += __logf(fmaf(alpha, dh, sel_lh));
    }

    // ---- logdet: lanes {cc, cc+16, cc+32, cc+48} hold row cc's partials ---
    ld_acc += __shfl_down(ld_acc, 32, 64);
    ld_acc += __shfl_down(ld_acc, 16, 64);
    if (q == 0)
        out[(size_t)M_ROWS * 64 + row_base + cc] = ld_acc;
}

extern "C" void kernel_launch(void* const* d_in, const int* in_sizes, int n_in,
                              void* d_out, int out_size, void* d_ws, size_t ws_size,
                              hipStream_t stream) {
    const float* c = (const float*)d_in[0];   // (M, 16)
    const float* z = (const float*)d_in[1];   // (M, 64)
    const float* W = (const float*)d_in[2];   // (48, 1056)
    const float* b = (const float*)d_in[3];   // (1056,)
    float* out = (float*)d_out;               // M*64 (x) then M (logdet)
    short* WB  = (short*)d_ws;                // 98304 bf16 = 192 KiB

    pack_W<<<(32 * 3 * 2 * 64 * 8) / 256, 256, 0, stream>>>(W, b, WB);
    fused_kernel<<<M_ROWS / BM, 256, 0, stream>>>(z, c, WB, out);
}

// Round 5
// 139.058 us; speedup vs baseline: 4.3096x; 1.4351x over previous
//
#include <hip/hip_runtime.h>
#include <hip/hip_bf16.h>
#include <math.h>

#define M_ROWS 65536
#define NSPLINE 32
#define BM 64            // rows per block
#define WROWS 16         // rows per wave
#define GROUP 4          // splines per iteration
#define NITER (NSPLINE / GROUP)   // 8
#define YSTRIDE 33       // LDS row stride (odd -> conflict-free reads)
#define WB_ELEMS (32 * 3 * 2 * 64 * 8)   // 98304 bf16 per buffer (hi / lo)

typedef __attribute__((ext_vector_type(8))) short short8;
typedef __attribute__((ext_vector_type(4))) float floatx4;

__device__ __forceinline__ short f2bf(float f) {
    union { __hip_bfloat16 h; short s; } u;
    u.h = __float2bfloat16(f);
    return u.s;
}
__device__ __forceinline__ float bf2f(short s) {
    union { unsigned int u; float f; } u;
    u.u = ((unsigned int)(unsigned short)s) << 16;
    return u.f;
}

// Accurate-enough softplus: log(1+e^t) = t/2 + log(2*cosh(t/2)).
// Even Taylor in u=t^2 through u^4; |err| <= ~5e-6 for |t| <= 1.1
// (verified against log1p at t=-1,0,1). Exact log1pf fallback outside
// (P ~ 1e-7 per eval for y ~ N(0,0.21)).
__device__ __forceinline__ float softplus_fast(float t) {
    float u = t * t;
    if (u > 1.21f) return log1pf(__expf(t));   // rare, exact
    float p = fmaf(u, -2.6352e-5f, 3.4722222e-4f);
    p = fmaf(u, p, -5.2083333e-3f);
    p = fmaf(u, p, 0.125f);
    p = fmaf(u, p, 0.69314718f);
    return fmaf(t, 0.5f, p);
}

// ---------------------------------------------------------------------------
// Pack W (48x1056 fp32) + bias (1056) into MFMA B-fragment layout as a
// SPLIT bf16 pair: WBhi = bf16(v), WBlo = bf16(v - float(WBhi)).
// Layout WB[sp][t][half][lane][j]:
//   col = sp*33 + t*16 + (lane&15)
//   k   = half*32 + (lane>>4)*8 + j  (k<48: W[k][col]; k==48: bias; else 0)
// Scatter form (verified: Output 0 passed with this pack in R2/R3).
// ---------------------------------------------------------------------------
__global__ void pack_W(const float* __restrict__ W, const float* __restrict__ b,
                       short* __restrict__ WBhi, short* __restrict__ WBlo) {
    int t0 = blockIdx.x * 256 + threadIdx.x;      // over 49*1056
    if (t0 >= 49 * 1056) return;
    int k   = t0 / 1056;
    int col = t0 % 1056;
    float v = (k < 48) ? W[t0] : b[col];
    int sp = col / 33, cl = col % 33;
    int t  = cl >> 4;                 // 0,1,2
    int lane = ((k & 31) >> 3) * 16 + (cl & 15);
    int half = k >> 5;
    int j    = k & 7;
    int idx = ((((sp * 3 + t) * 2 + half) * 64) + lane) * 8 + j;
    short hi = f2bf(v);
    WBhi[idx] = hi;
    WBlo[idx] = f2bf(v - bf2f(hi));
}

// ---------------------------------------------------------------------------
// Fused: split-bf16 MFMA GEMM (y = [z2,c,1] @ [W;b], ~fp32 accurate)
// -> LDS transpose -> spline with R1-proven numerics (IEEE divides,
// __expf/__logf placement identical to the passing round-1 kernel; only
// log1pf(__expf(t)) replaced by the bounded-error softplus_fast).
// ---------------------------------------------------------------------------
__global__ void __launch_bounds__(256, 4) fused_kernel(
    const float* __restrict__ z, const float* __restrict__ c,
    const short* __restrict__ WBhi, const short* __restrict__ WBlo,
    float* __restrict__ out)
{
    __shared__ float lds_y[4 * 64 * YSTRIDE];    // 33.8 KB, per-wave regions

    const int tid  = threadIdx.x;
    const int w    = tid >> 6;
    const int lane = tid & 63;
    const int q    = lane >> 4;        // quad 0..3
    const int cc   = lane & 15;
    const int row_base = blockIdx.x * BM + w * WROWS;
    float* lds_wv = lds_y + w * (64 * YSTRIDE);

    // ---- z2 passthrough: out[:, :32] = z[:, 32:64] for this wave's rows ----
    #pragma unroll
    for (int it = 0; it < 2; ++it) {
        int idx = it * 64 + lane;                 // 0..127 = 16 rows x 8 float4
        int rr  = row_base + (idx >> 3);
        int v4  = idx & 7;
        float4 val = *(const float4*)(z + (size_t)rr * 64 + 32 + v4 * 4);
        *(float4*)(out + (size_t)rr * 64 + v4 * 4) = val;
    }

    // ---- A fragments, split hi/lo: A[m=cc][k], k=(q*8+j) ------------------
    short8 a0h, a0l, a1h, a1l;
    {
        const float* zr = z + (size_t)(row_base + cc) * 64 + 32;
        float4 v0 = *(const float4*)(zr + q * 8);
        float4 v1 = *(const float4*)(zr + q * 8 + 4);
        float va[8] = {v0.x, v0.y, v0.z, v0.w, v1.x, v1.y, v1.z, v1.w};
        #pragma unroll
        for (int j = 0; j < 8; ++j) {
            short hi = f2bf(va[j]);
            a0h[j] = hi;
            a0l[j] = f2bf(va[j] - bf2f(hi));
        }
        if (q < 2) {
            const float* cr = c + (size_t)(row_base + cc) * 16 + q * 8;
            float4 u0 = *(const float4*)cr;
            float4 u1 = *(const float4*)(cr + 4);
            float vb[8] = {u0.x, u0.y, u0.z, u0.w, u1.x, u1.y, u1.z, u1.w};
            #pragma unroll
            for (int j = 0; j < 8; ++j) {
                short hi = f2bf(vb[j]);
                a1h[j] = hi;
                a1l[j] = f2bf(vb[j] - bf2f(hi));
            }
        } else {
            #pragma unroll
            for (int j = 0; j < 8; ++j) { a1h[j] = 0; a1l[j] = 0; }
            if (q == 2) a1h[0] = (short)0x3F80;   // bf16 1.0 at k=48 (bias row)
        }
    }

    float ld_acc = 0.0f;

    #pragma unroll 1
    for (int g = 0; g < NITER; ++g) {
        __syncthreads();   // prior iteration's LDS reads are done

        // ---- GEMM: 4 splines x 3 col-tiles, 6 MFMA each (split product) --
        #pragma unroll
        for (int sp = 0; sp < GROUP; ++sp) {
            const int spg = g * GROUP + sp;
            #pragma unroll
            for (int t = 0; t < 3; ++t) {
                const size_t off = (size_t)(spg * 3 + t) * 128 + lane;
                const short8* ph = (const short8*)WBhi + off;
                const short8* pl = (const short8*)WBlo + off;
                short8 bh0 = ph[0];
                short8 bh1 = ph[64];
                short8 bl0 = pl[0];
                short8 bl1 = pl[64];
                floatx4 acc = {0.f, 0.f, 0.f, 0.f};
                // cross terms first (small), then hi*hi
                acc = __builtin_amdgcn_mfma_f32_16x16x32_bf16(a0l, bh0, acc, 0, 0, 0);
                acc = __builtin_amdgcn_mfma_f32_16x16x32_bf16(a1l, bh1, acc, 0, 0, 0);
                acc = __builtin_amdgcn_mfma_f32_16x16x32_bf16(a0h, bl0, acc, 0, 0, 0);
                acc = __builtin_amdgcn_mfma_f32_16x16x32_bf16(a1h, bl1, acc, 0, 0, 0);
                acc = __builtin_amdgcn_mfma_f32_16x16x32_bf16(a0h, bh0, acc, 0, 0, 0);
                acc = __builtin_amdgcn_mfma_f32_16x16x32_bf16(a1h, bh1, acc, 0, 0, 0);
                // D layout: col = cc (=lane&15), row = q*4 + reg
                if (t < 2 || cc == 0) {
                    float* dst = lds_wv + (sp * 16 + q * 4) * YSTRIDE + t * 16 + cc;
                    dst[0]          = acc[0];
                    dst[YSTRIDE]    = acc[1];
                    dst[2 * YSTRIDE]= acc[2];
                    dst[3 * YSTRIDE]= acc[3];
                }
            }
        }
        __syncthreads();

        // ---- spline: task = (row=cc, spline n=g*4+q), all 64 lanes busy --
        const int n = g * GROUP + q;
        const float* my = lds_wv + (q * 16 + cc) * YSTRIDE;   // = lane*33
        const float in = z[(size_t)(row_base + cc) * 64 + n];

        float wd[16];
        float sew = 0.f;
        #pragma unroll
        for (int i = 0; i < 16; ++i) {
            float e = __expf(my[17 + i]);
            wd[i] = e; sew += e;
        }
        const float inv_sew = 0.984f / sew;        // (1 - 16*MIN_BW)/sum
        #pragma unroll
        for (int i = 0; i < 16; ++i) wd[i] = 0.001f + wd[i] * inv_sew;

        float h[17];
        #pragma unroll
        for (int i = 0; i < 17; ++i)
            h[i] = softplus_fast(my[i]) + 0.001f;  // softplus + 0.001

        float area = 0.f;
        #pragma unroll
        for (int i = 0; i < 16; ++i) area += (h[i] + h[i + 1]) * 0.5f * wd[i];
        const float inv_area = 0.999f / area;      // (1 - MIN_BH)/area
        #pragma unroll
        for (int i = 0; i < 17; ++i) h[i] = 0.001f + h[i] * inv_area;

        float loc = 0.f, cdfl = 0.f;
        float sel_loc = 0.f, sel_w = wd[0], sel_cdf = 0.f;
        float sel_lh = h[0], sel_rh = h[1];
        #pragma unroll
        for (int bn = 1; bn < 16; ++bn) {
            cdfl = fmaf((h[bn - 1] + h[bn]) * 0.5f, wd[bn - 1], cdfl);
            loc += wd[bn - 1];
            if (in >= loc) {                        // monotone: last true wins
                sel_loc = loc; sel_w = wd[bn]; sel_cdf = cdfl;
                sel_lh = h[bn]; sel_rh = h[bn + 1];
            }
        }

        const float alpha = (in - sel_loc) / sel_w;
        const float dh    = sel_rh - sel_lh;
        float o = ((0.5f * dh * sel_w) * alpha + sel_lh * sel_w) * alpha + sel_cdf;
        o = fminf(fmaxf(o, 0.0f), 1.0f);
        out[(size_t)(row_base + cc) * 64 + 32 + n] = o;
        ld_acc += __logf(fmaf(alpha, dh, sel_lh));
    }

    // ---- logdet: lanes {cc, cc+16, cc+32, cc+48} hold row cc's partials ---
    ld_acc += __shfl_down(ld_acc, 32, 64);
    ld_acc += __shfl_down(ld_acc, 16, 64);
    if (q == 0)
        out[(size_t)M_ROWS * 64 + row_base + cc] = ld_acc;
}

extern "C" void kernel_launch(void* const* d_in, const int* in_sizes, int n_in,
                              void* d_out, int out_size, void* d_ws, size_t ws_size,
                              hipStream_t stream) {
    const float* c = (const float*)d_in[0];   // (M, 16)
    const float* z = (const float*)d_in[1];   // (M, 64)
    const float* W = (const float*)d_in[2];   // (48, 1056)
    const float* b = (const float*)d_in[3];   // (1056,)
    float* out = (float*)d_out;               // M*64 (x) then M (logdet)
    short* WBhi = (short*)d_ws;               // 98304 bf16 hi
    short* WBlo = WBhi + WB_ELEMS;            // 98304 bf16 lo

    hipMemsetAsync(WBhi, 0, 2 * WB_ELEMS * sizeof(short), stream);
    pack_W<<<(49 * 1056 + 255) / 256, 256, 0, stream>>>(W, b, WBhi, WBlo);
    fused_kernel<<<M_ROWS / BM, 256, 0, stream>>>(z, c, WBhi, WBlo, out);
}